// Round 5
// baseline (228.608 us; speedup 1.0000x reference)
//
#include <hip/hip_runtime.h>

// GraphDecoder (NRI) — round 14: BARRIER-FREE edge K-loop. R13 proved the
// binder is the per-iter barrier cadence (conflicts->0, occupancy 29%, yet
// slower with half the MFMA/barrier). edge10: A-fragments built in regs
// directly from S2 (per-lane 16B global, kk-chunked layout) + R (read-only
// LDS broadcast, written once); B-fragments global->regs (edge8-proven
// numerics); ZERO __syncthreads / LDS writes / glds in the 32-iter loop.
// LDS 5KB; acc[2][2]=64 regs; (256,3). XCD swizzle kept. prep/outmlp kept.
// B=32, N=64, F=128, K=4, H=M=NH=256, E=4032.

#define B_ 32
#define N_ 64
#define F_ 128
#define K_ 4
#define E_ 4032

// ws layout (bytes): total 9,961,472 <= proven 9,994,240
#define WS_W2T 0u
#define WS_R   524288u
#define WS_S   4718592u
#define WS_AGG 8912896u

typedef unsigned short u16;
typedef u16    u16x4  __attribute__((ext_vector_type(4)));
typedef u16    u16x8  __attribute__((ext_vector_type(8)));
typedef __bf16 bf16x8 __attribute__((ext_vector_type(8)));
typedef float  f32x4  __attribute__((ext_vector_type(4)));
typedef float  f32x16 __attribute__((ext_vector_type(16)));

__device__ __forceinline__ u16 f2bf(float f) {
    unsigned u; __builtin_memcpy(&u, &f, 4);
    return (u16)((u + 0x7FFFu + ((u >> 16) & 1u)) >> 16);
}
__device__ __forceinline__ float bf2f(u16 u) {
    unsigned v = ((unsigned)u) << 16;
    float f; __builtin_memcpy(&f, &v, 4); return f;
}

// raw barrier for outmlp (LDS-only handoff; keeps vmem prefetch in flight)
#define LBAR() do { \
    asm volatile("s_waitcnt lgkmcnt(0)" ::: "memory"); \
    __builtin_amdgcn_s_barrier(); \
    __builtin_amdgcn_sched_barrier(0); \
} while (0)

// ---------------- fused prep (W2 -> cf bf16 chunks) + R/S2 tables ----------------
// S2 kk-chunked: S2[((k*8+kc)*2048 + b*64 + row)*32 + kk_local]  (kc = n>>5)
__global__ __launch_bounds__(256) void prep_rs_kernel(
    const float* __restrict__ W2, const float* __restrict__ x,
    const float* __restrict__ W1, const float* __restrict__ b1,
    u16* __restrict__ W2t, u16* __restrict__ R, u16* __restrict__ S)
{
    __shared__ u16 ldsA[64 * 136];
    __shared__ u16 ldsW[32 * 136];
    const int tid = threadIdx.x;

    if (blockIdx.x < 1024) {
        // W2t[chunk=k*8+kc][g=ks2*2+lh][n(256)][e(8)] = W2[k][kk][n]
        unsigned gid = blockIdx.x * 256u + tid;
        unsigned chunk = gid >> 13, r = gid & 8191u;
        unsigned g = r >> 11, n = (r >> 3) & 255u, e = r & 7u;
        unsigned k = chunk >> 3, kc = chunk & 7u, ks2 = g >> 1, lhh = g & 1u;
        unsigned kk = kc * 32u + ks2 * 16u + lhh * 8u + e;
        W2t[gid] = f2bf(W2[(k * 256u + kk) * 256u + n]);
        return;
    }

    const int lane = tid & 63, w = tid >> 6;
    const int quad = lane >> 4, mloc = lane & 15;
    const int bx = blockIdx.x - 1024;
    const int k = bx >> 6, half = (bx >> 5) & 1, b = bx & 31;

    for (int idx = tid; idx < 2048; idx += 256) {
        int row = idx >> 5, c4 = idx & 31;
        f32x4 v = *(const f32x4*)&x[(b * 64 + row) * 128 + c4 * 4];
        u16x4 o;
#pragma unroll
        for (int e = 0; e < 4; ++e) o[e] = f2bf(v[e]);
        *(u16x4*)&ldsA[row * 136 + c4 * 4] = o;
    }
    __syncthreads();

    bf16x8 aF[4];
#pragma unroll
    for (int ks = 0; ks < 4; ++ks)
        aF[ks] = *(const bf16x8*)&ldsA[(w * 16 + mloc) * 136 + quad * 8 + ks * 32];

    u16* dst = half ? S : R;
    for (int c = 0; c < 8; ++c) {
        __syncthreads();
        for (int idx = tid; idx < 4096; idx += 256) {
            int n = idx & 31, f = idx >> 5;
            ldsW[n * 136 + f] = f2bf(W1[(k * 256 + half * 128 + f) * 256 + c * 32 + n]);
        }
        __syncthreads();
#pragma unroll
        for (int nt = 0; nt < 2; ++nt) {
            f32x4 acc = (f32x4){0.f, 0.f, 0.f, 0.f};
            const int boff = (nt * 16 + mloc) * 136 + quad * 8;
#pragma unroll
            for (int ks = 0; ks < 4; ++ks)
                acc = __builtin_amdgcn_mfma_f32_16x16x32_bf16(
                    aF[ks], *(const bf16x8*)&ldsW[boff + ks * 32], acc, 0, 0, 0);
            const int n = c * 32 + nt * 16 + mloc;
            const float bias = half ? 0.f : b1[k * 256 + n];
#pragma unroll
            for (int r = 0; r < 4; ++r) {
                int row = w * 16 + quad * 4 + r;
                if (half) {
                    dst[((size_t)((k * 8 + c) * 2048 + b * 64 + row)) * 32 + nt * 16 + mloc]
                        = f2bf(acc[r] + bias);
                } else {
                    dst[((size_t)(k * 2048 + b * 64 + row)) * 256 + n] = f2bf(acc[r] + bias);
                }
            }
        }
    }
}

// ---------------- edge kernel: barrier-free K-loop, all operands in regs ----------------
__global__ __launch_bounds__(256, 3) void edge10_kernel(
    const u16* __restrict__ R, const u16* __restrict__ S2,
    const float* __restrict__ rel, const u16* __restrict__ W2t,
    const float* __restrict__ b2, u16* __restrict__ aggb)
{
    __shared__ float Rf[4][256];    // receiver R rows, f32 — written once, read-only
    __shared__ float rtS[4][64];    // rel_type [k][j], self=0 — written once

    const int tid  = threadIdx.x;
    const int lane = tid & 63;
    const int w    = tid >> 6;      // n-quarter 0..3
    const int l31  = lane & 31;
    const int lh   = lane >> 5;
    // XCD-aware swizzle (bijective: 2048 % 8 == 0): 64 blocks sharing b per XCD
    // -> S2/R/rel/W2t slices L2-resident (FETCH 22.4->8MB proven R10/R11).
    const int bid  = ((blockIdx.x & 7) << 8) | (blockIdx.x >> 3);
    const int b    = bid >> 6;
    const int i    = bid & 63;      // receiver node

    // rtS: self-edge trick (j==i -> 0; else jj = j - (j>i)) — 1 elem/thread
    {
        const int k = tid >> 6, j = tid & 63;
        float v = 0.f;
        if (j != i) v = rel[((size_t)(b * E_) + i * 63 + (j - (j > i))) * 4 + k];
        rtS[k][j] = v;
    }
    // Rf: unpack receiver R row to f32 — 4 elems/thread
    {
        const int k = tid >> 6, e4 = tid & 63;
        u16x4 t4 = *(const u16x4*)&R[((size_t)(k * 2048 + b * 64 + i)) * 256 + e4 * 4];
#pragma unroll
        for (int e = 0; e < 4; ++e) Rf[k][e4 * 4 + e] = bf2f(t4[e]);
    }
    __syncthreads();    // the ONLY barrier in this kernel

    // per-lane steady bases
    const u16* Sb0 = S2 + (size_t)(b * 64 + l31) * 32 + lh * 8;        // sender row l31
    const u16* Sb1 = S2 + (size_t)(b * 64 + 32 + l31) * 32 + lh * 8;   // sender row 32+l31
    const u16* Wb  = W2t + lh * 2048 + (w * 64 + l31) * 8;             // B base (n-quarter w)

    float amsg[2] = {0.f, 0.f};

    for (int kT = 0; kT < 4; ++kT) {
        f32x16 acc[2][2];
#pragma unroll
        for (int mt = 0; mt < 2; ++mt)
#pragma unroll
            for (int nt = 0; nt < 2; ++nt) acc[mt][nt] = (f32x16)(0.f);

#pragma unroll
        for (int kc = 0; kc < 8; ++kc) {
            const int it = kT * 8 + kc;
#pragma unroll
            for (int ks2 = 0; ks2 < 2; ++ks2) {
                // S: per-lane 16B loads (L2-hot, kk-chunked layout)
                u16x8 s0 = *(const u16x8*)(Sb0 + (size_t)it * 65536 + ks2 * 16);
                u16x8 s1 = *(const u16x8*)(Sb1 + (size_t)it * 65536 + ks2 * 16);
                // R: wave-broadcast LDS read (2 addrs per wave, conflict-free)
                const float* rp = &Rf[kT][kc * 32 + ks2 * 16 + lh * 8];
                f32x4 r0 = *(const f32x4*)rp, r1 = *(const f32x4*)(rp + 4);
                // build A fragments in regs: relu(R + S)
                bf16x8 A0, A1;
#pragma unroll
                for (int e = 0; e < 4; ++e) {
                    A0[e]     = (__bf16)fmaxf(r0[e] + bf2f(s0[e]),     0.f);
                    A0[4 + e] = (__bf16)fmaxf(r1[e] + bf2f(s0[4 + e]), 0.f);
                    A1[e]     = (__bf16)fmaxf(r0[e] + bf2f(s1[e]),     0.f);
                    A1[4 + e] = (__bf16)fmaxf(r1[e] + bf2f(s1[4 + e]), 0.f);
                }
                // B fragments: coalesced 16B/lane global loads (L2-resident)
                const u16* wp = Wb + (size_t)it * 8192 + ks2 * 4096;
                bf16x8 B0 = *(const bf16x8*)(wp);
                bf16x8 B1 = *(const bf16x8*)(wp + 256);
                acc[0][0] = __builtin_amdgcn_mfma_f32_32x32x16_bf16(A0, B0, acc[0][0], 0, 0, 0);
                acc[0][1] = __builtin_amdgcn_mfma_f32_32x32x16_bf16(A0, B1, acc[0][1], 0, 0, 0);
                acc[1][0] = __builtin_amdgcn_mfma_f32_32x32x16_bf16(A1, B0, acc[1][0], 0, 0, 0);
                acc[1][1] = __builtin_amdgcn_mfma_f32_32x32x16_bf16(A1, B1, acc[1][1], 0, 0, 0);
            }
        }

        // per-k epilogue: bias + relu + rel_type-weighted row fold
#pragma unroll
        for (int nt = 0; nt < 2; ++nt) {
            const float bias = b2[kT * 256 + w * 64 + nt * 32 + l31];
#pragma unroll
            for (int mt = 0; mt < 2; ++mt) {
                float s = 0.f;
#pragma unroll
                for (int rq = 0; rq < 4; ++rq) {
                    f32x4 rt4 = *(const f32x4*)&rtS[kT][mt * 32 + rq * 8 + 4 * lh];
#pragma unroll
                    for (int e = 0; e < 4; ++e) {
                        float v = acc[mt][nt][rq * 4 + e] + bias;
                        v = v > 0.f ? v : 0.f;
                        s += rt4[e] * v;
                    }
                }
                amsg[nt] += s;
            }
        }
    }

    // fold lh halves; unique writer per slot
#pragma unroll
    for (int nt = 0; nt < 2; ++nt) {
        float s = amsg[nt] + __shfl_xor(amsg[nt], 32);
        if (lh == 0)
            aggb[(size_t)(b * 64 + i) * 256 + w * 64 + nt * 32 + l31] = f2bf(s);
    }
}

// ---------------- output MLP: reg-prefetched weight chunks + raw barriers ----------------
__global__ __launch_bounds__(256) void outmlp3_kernel(
    const float* __restrict__ x, const u16* __restrict__ aggb,
    const float* __restrict__ Wo1, const float* __restrict__ bo1,
    const float* __restrict__ Wo2, const float* __restrict__ bo2,
    const float* __restrict__ Wo3, const float* __restrict__ bo3,
    float* __restrict__ out)
{
    __shared__ u16 wch[4][256][8];   // cf weight chunk [g][n][8kk]
    __shared__ u16 p1S[32 * 264];
    __shared__ u16 p2S[32 * 264];
    const int tid = threadIdx.x, lane = tid & 63, w = tid >> 6;
    const int quad = lane >> 4, mloc = lane & 15;
    const int row0 = blockIdx.x * 32;

    {   // ---- L1: K=384 (12 chunks), N=256, aug=[x|agg] ----
        f32x4 acc[2][4];
#pragma unroll
        for (int mt = 0; mt < 2; ++mt)
#pragma unroll
            for (int nt = 0; nt < 4; ++nt) acc[mt][nt] = (f32x4){0.f, 0.f, 0.f, 0.f};
        float wr[32];
#pragma unroll
        for (int g = 0; g < 4; ++g)
#pragma unroll
            for (int e = 0; e < 8; ++e) wr[g * 8 + e] = Wo1[(g * 8 + e) * 256 + tid];
        for (int kk = 0; kk < 12; ++kk) {
            bf16x8 aF[2];
#pragma unroll
            for (int mt = 0; mt < 2; ++mt) {
                const int row = row0 + mt * 16 + mloc;
                if (kk < 4) {
                    u16x8 t;
#pragma unroll
                    for (int e = 0; e < 8; ++e) t[e] = f2bf(x[row * 128 + kk * 32 + quad * 8 + e]);
                    __builtin_memcpy(&aF[mt], &t, 16);
                } else {
                    aF[mt] = *(const bf16x8*)&aggb[(size_t)row * 256 + (kk - 4) * 32 + quad * 8];
                }
            }
#pragma unroll
            for (int g = 0; g < 4; ++g) {
                u16x8 o;
#pragma unroll
                for (int e = 0; e < 8; ++e) o[e] = f2bf(wr[g * 8 + e]);
                *(u16x8*)&wch[g][tid][0] = o;
            }
            if (kk + 1 < 12) {
#pragma unroll
                for (int g = 0; g < 4; ++g)
#pragma unroll
                    for (int e = 0; e < 8; ++e) wr[g * 8 + e] = Wo1[((kk + 1) * 32 + g * 8 + e) * 256 + tid];
            }
            LBAR();
#pragma unroll
            for (int nt = 0; nt < 4; ++nt) {
                bf16x8 bF = *(const bf16x8*)&wch[quad][w * 64 + nt * 16 + mloc][0];
#pragma unroll
                for (int mt = 0; mt < 2; ++mt)
                    acc[mt][nt] = __builtin_amdgcn_mfma_f32_16x16x32_bf16(aF[mt], bF, acc[mt][nt], 0, 0, 0);
            }
            LBAR();
        }
#pragma unroll
        for (int nt = 0; nt < 4; ++nt) {
            const int n = w * 64 + nt * 16 + mloc;
            const float bias = bo1[n];
#pragma unroll
            for (int mt = 0; mt < 2; ++mt)
#pragma unroll
                for (int r = 0; r < 4; ++r) {
                    float v = acc[mt][nt][r] + bias;
                    p1S[(mt * 16 + quad * 4 + r) * 264 + n] = f2bf(v > 0.f ? v : 0.f);
                }
        }
    }
    LBAR();
    {   // ---- L2: K=256 (8 chunks), N=256 ----
        f32x4 acc[2][4];
#pragma unroll
        for (int mt = 0; mt < 2; ++mt)
#pragma unroll
            for (int nt = 0; nt < 4; ++nt) acc[mt][nt] = (f32x4){0.f, 0.f, 0.f, 0.f};
        float wr[32];
#pragma unroll
        for (int g = 0; g < 4; ++g)
#pragma unroll
            for (int e = 0; e < 8; ++e) wr[g * 8 + e] = Wo2[(g * 8 + e) * 256 + tid];
        for (int kk = 0; kk < 8; ++kk) {
            bf16x8 aF[2];
#pragma unroll
            for (int mt = 0; mt < 2; ++mt)
                aF[mt] = *(const bf16x8*)&p1S[(mt * 16 + mloc) * 264 + kk * 32 + quad * 8];
#pragma unroll
            for (int g = 0; g < 4; ++g) {
                u16x8 o;
#pragma unroll
                for (int e = 0; e < 8; ++e) o[e] = f2bf(wr[g * 8 + e]);
                *(u16x8*)&wch[g][tid][0] = o;
            }
            if (kk + 1 < 8) {
#pragma unroll
                for (int g = 0; g < 4; ++g)
#pragma unroll
                    for (int e = 0; e < 8; ++e) wr[g * 8 + e] = Wo2[((kk + 1) * 32 + g * 8 + e) * 256 + tid];
            }
            LBAR();
#pragma unroll
            for (int nt = 0; nt < 4; ++nt) {
                bf16x8 bF = *(const bf16x8*)&wch[quad][w * 64 + nt * 16 + mloc][0];
#pragma unroll
                for (int mt = 0; mt < 2; ++mt)
                    acc[mt][nt] = __builtin_amdgcn_mfma_f32_16x16x32_bf16(aF[mt], bF, acc[mt][nt], 0, 0, 0);
            }
            LBAR();
        }
#pragma unroll
        for (int nt = 0; nt < 4; ++nt) {
            const int n = w * 64 + nt * 16 + mloc;
            const float bias = bo2[n];
#pragma unroll
            for (int mt = 0; mt < 2; ++mt)
#pragma unroll
                for (int r = 0; r < 4; ++r) {
                    float v = acc[mt][nt][r] + bias;
                    p2S[(mt * 16 + quad * 4 + r) * 264 + n] = f2bf(v > 0.f ? v : 0.f);
                }
        }
    }
    LBAR();
    {   // ---- L3: K=256 (8 chunks), N=128, residual ----
        f32x4 acc[2][2];
#pragma unroll
        for (int mt = 0; mt < 2; ++mt)
#pragma unroll
            for (int nt = 0; nt < 2; ++nt) acc[mt][nt] = (f32x4){0.f, 0.f, 0.f, 0.f};
        const int sn = tid & 127, sh = tid >> 7;
        float wr[16];
#pragma unroll
        for (int g2 = 0; g2 < 2; ++g2)
#pragma unroll
            for (int e = 0; e < 8; ++e) wr[g2 * 8 + e] = Wo3[((sh * 2 + g2) * 8 + e) * 128 + sn];
        for (int kk = 0; kk < 8; ++kk) {
            bf16x8 aF[2];
#pragma unroll
            for (int mt = 0; mt < 2; ++mt)
                aF[mt] = *(const bf16x8*)&p2S[(mt * 16 + mloc) * 264 + kk * 32 + quad * 8];
#pragma unroll
            for (int g2 = 0; g2 < 2; ++g2) {
                const int g = sh * 2 + g2;
                u16x8 o;
#pragma unroll
                for (int e = 0; e < 8; ++e) o[e] = f2bf(wr[g2 * 8 + e]);
                *(u16x8*)&wch[g][sn][0] = o;
            }
            if (kk + 1 < 8) {
#pragma unroll
                for (int g2 = 0; g2 < 2; ++g2)
#pragma unroll
                    for (int e = 0; e < 8; ++e)
                        wr[g2 * 8 + e] = Wo3[((kk + 1) * 32 + (sh * 2 + g2) * 8 + e) * 128 + sn];
            }
            LBAR();
#pragma unroll
            for (int nt = 0; nt < 2; ++nt) {
                bf16x8 bF = *(const bf16x8*)&wch[quad][w * 32 + nt * 16 + mloc][0];
#pragma unroll
                for (int mt = 0; mt < 2; ++mt)
                    acc[mt][nt] = __builtin_amdgcn_mfma_f32_16x16x32_bf16(aF[mt], bF, acc[mt][nt], 0, 0, 0);
            }
            LBAR();
        }
#pragma unroll
        for (int nt = 0; nt < 2; ++nt) {
            const int n = w * 32 + nt * 16 + mloc;
            const float bias = bo3[n];
#pragma unroll
            for (int mt = 0; mt < 2; ++mt)
#pragma unroll
                for (int r = 0; r < 4; ++r) {
                    const int grow = row0 + mt * 16 + quad * 4 + r;
                    out[grow * 128 + n] = x[grow * 128 + n] + acc[mt][nt][r] + bias;
                }
        }
    }
}

extern "C" void kernel_launch(void* const* d_in, const int* in_sizes, int n_in,
                              void* d_out, int out_size, void* d_ws, size_t ws_size,
                              hipStream_t stream) {
    const float* x   = (const float*)d_in[0];
    const float* rel = (const float*)d_in[1];
    const float* W1  = (const float*)d_in[4];
    const float* b1  = (const float*)d_in[5];
    const float* W2  = (const float*)d_in[6];
    const float* b2  = (const float*)d_in[7];
    const float* Wo1 = (const float*)d_in[8];
    const float* bo1 = (const float*)d_in[9];
    const float* Wo2 = (const float*)d_in[10];
    const float* bo2 = (const float*)d_in[11];
    const float* Wo3 = (const float*)d_in[12];
    const float* bo3 = (const float*)d_in[13];
    float* out = (float*)d_out;

    char* ws = (char*)d_ws;
    u16* W2t  = (u16*)(ws + WS_W2T);
    u16* R    = (u16*)(ws + WS_R);
    u16* S2   = (u16*)(ws + WS_S);
    u16* aggb = (u16*)(ws + WS_AGG);

    prep_rs_kernel<<<1280, 256, 0, stream>>>(W2, x, W1, b1, W2t, R, S2);
    edge10_kernel<<<2048, 256, 0, stream>>>(R, S2, rel, W2t, b2, aggb);
    outmlp3_kernel<<<64, 256, 0, stream>>>(x, aggb, Wo1, bo1, Wo2, bo2, Wo3, bo3, out);
}

// Round 6
// 207.053 us; speedup vs baseline: 1.1041x; 1.1041x over previous
//
#include <hip/hip_runtime.h>

// GraphDecoder (NRI) — round 15: per-kT staged H. R14 showed the binder is
// 4x-redundant A-build VALU (72us busy vs 27us MFMA floor); R11/R13 showed
// per-iter barriers cost ~same. edge11: build the full 64x256 H tile for one
// k-type into LDS ONCE (no redundancy, conflict-free writes), 1 barrier, then
// 8 straight-line MFMA iters (ds_read A + reg B, ~2k MFMA-cyc between syncs),
// 1 barrier. 8 barriers/block. B stays global->regs (n-quarter split, 1x L2).
// LDS 37KB, acc 64 regs, (256,3). XCD swizzle kept. prep/outmlp unchanged.
// B=32, N=64, F=128, K=4, H=M=NH=256, E=4032.

#define B_ 32
#define N_ 64
#define F_ 128
#define K_ 4
#define E_ 4032

// ws layout (bytes): total 9,961,472 <= proven 9,994,240
#define WS_W2T 0u
#define WS_R   524288u
#define WS_S   4718592u
#define WS_AGG 8912896u

typedef unsigned short u16;
typedef u16    u16x4  __attribute__((ext_vector_type(4)));
typedef u16    u16x8  __attribute__((ext_vector_type(8)));
typedef __bf16 bf16x8 __attribute__((ext_vector_type(8)));
typedef float  f32x4  __attribute__((ext_vector_type(4)));
typedef float  f32x16 __attribute__((ext_vector_type(16)));

__device__ __forceinline__ u16 f2bf(float f) {
    unsigned u; __builtin_memcpy(&u, &f, 4);
    return (u16)((u + 0x7FFFu + ((u >> 16) & 1u)) >> 16);
}
__device__ __forceinline__ float bf2f(u16 u) {
    unsigned v = ((unsigned)u) << 16;
    float f; __builtin_memcpy(&f, &v, 4); return f;
}

// raw barrier for outmlp (LDS-only handoff; keeps vmem prefetch in flight)
#define LBAR() do { \
    asm volatile("s_waitcnt lgkmcnt(0)" ::: "memory"); \
    __builtin_amdgcn_s_barrier(); \
    __builtin_amdgcn_sched_barrier(0); \
} while (0)

// ---------------- fused prep (W2 -> cf bf16 chunks) + R/S2 tables ----------------
// S2 kk-chunked: S2[((k*8+kc)*2048 + b*64 + row)*32 + kk_local]  (kc = kk>>5)
__global__ __launch_bounds__(256) void prep_rs_kernel(
    const float* __restrict__ W2, const float* __restrict__ x,
    const float* __restrict__ W1, const float* __restrict__ b1,
    u16* __restrict__ W2t, u16* __restrict__ R, u16* __restrict__ S)
{
    __shared__ u16 ldsA[64 * 136];
    __shared__ u16 ldsW[32 * 136];
    const int tid = threadIdx.x;

    if (blockIdx.x < 1024) {
        // W2t[chunk=k*8+kc][g=ks2*2+lh][n(256)][e(8)] = W2[k][kk][n]
        unsigned gid = blockIdx.x * 256u + tid;
        unsigned chunk = gid >> 13, r = gid & 8191u;
        unsigned g = r >> 11, n = (r >> 3) & 255u, e = r & 7u;
        unsigned k = chunk >> 3, kc = chunk & 7u, ks2 = g >> 1, lhh = g & 1u;
        unsigned kk = kc * 32u + ks2 * 16u + lhh * 8u + e;
        W2t[gid] = f2bf(W2[(k * 256u + kk) * 256u + n]);
        return;
    }

    const int lane = tid & 63, w = tid >> 6;
    const int quad = lane >> 4, mloc = lane & 15;
    const int bx = blockIdx.x - 1024;
    const int k = bx >> 6, half = (bx >> 5) & 1, b = bx & 31;

    for (int idx = tid; idx < 2048; idx += 256) {
        int row = idx >> 5, c4 = idx & 31;
        f32x4 v = *(const f32x4*)&x[(b * 64 + row) * 128 + c4 * 4];
        u16x4 o;
#pragma unroll
        for (int e = 0; e < 4; ++e) o[e] = f2bf(v[e]);
        *(u16x4*)&ldsA[row * 136 + c4 * 4] = o;
    }
    __syncthreads();

    bf16x8 aF[4];
#pragma unroll
    for (int ks = 0; ks < 4; ++ks)
        aF[ks] = *(const bf16x8*)&ldsA[(w * 16 + mloc) * 136 + quad * 8 + ks * 32];

    u16* dst = half ? S : R;
    for (int c = 0; c < 8; ++c) {
        __syncthreads();
        for (int idx = tid; idx < 4096; idx += 256) {
            int n = idx & 31, f = idx >> 5;
            ldsW[n * 136 + f] = f2bf(W1[(k * 256 + half * 128 + f) * 256 + c * 32 + n]);
        }
        __syncthreads();
#pragma unroll
        for (int nt = 0; nt < 2; ++nt) {
            f32x4 acc = (f32x4){0.f, 0.f, 0.f, 0.f};
            const int boff = (nt * 16 + mloc) * 136 + quad * 8;
#pragma unroll
            for (int ks = 0; ks < 4; ++ks)
                acc = __builtin_amdgcn_mfma_f32_16x16x32_bf16(
                    aF[ks], *(const bf16x8*)&ldsW[boff + ks * 32], acc, 0, 0, 0);
            const int n = c * 32 + nt * 16 + mloc;
            const float bias = half ? 0.f : b1[k * 256 + n];
#pragma unroll
            for (int r = 0; r < 4; ++r) {
                int row = w * 16 + quad * 4 + r;
                if (half) {
                    dst[((size_t)((k * 8 + c) * 2048 + b * 64 + row)) * 32 + nt * 16 + mloc]
                        = f2bf(acc[r] + bias);
                } else {
                    dst[((size_t)(k * 2048 + b * 64 + row)) * 256 + n] = f2bf(acc[r] + bias);
                }
            }
        }
    }
}

// ---------------- edge kernel: per-kT staged H, 8 barriers total ----------------
__global__ __launch_bounds__(256, 3) void edge11_kernel(
    const u16* __restrict__ R, const u16* __restrict__ S2,
    const float* __restrict__ rel, const u16* __restrict__ W2t,
    const float* __restrict__ b2, u16* __restrict__ aggb)
{
    __shared__ u16   Hs[32][64][8];   // H tile for one kT: [g=kk-group][row][8kk] — 32KB
    __shared__ float Rf[4][256];      // receiver R rows, f32 — written once
    __shared__ float rtS[4][64];      // rel_type [k][j], self=0 — written once

    const int tid  = threadIdx.x;
    const int lane = tid & 63;
    const int w    = tid >> 6;        // n-quarter (MFMA) AND kk32-subgroup (build)
    const int l31  = lane & 31;
    const int lh   = lane >> 5;
    // XCD-aware swizzle (bijective: 2048 % 8 == 0): 64 blocks sharing b per XCD
    // -> S2/R/rel/W2t slices L2-resident (FETCH 22.4->8MB proven R10/R11).
    const int bid  = ((blockIdx.x & 7) << 8) | (blockIdx.x >> 3);
    const int b    = bid >> 6;
    const int i    = bid & 63;        // receiver node

    // rtS: self-edge trick (j==i -> 0; else jj = j - (j>i)) — 1 elem/thread
    {
        const int k = tid >> 6, j = tid & 63;
        float v = 0.f;
        if (j != i) v = rel[((size_t)(b * E_) + i * 63 + (j - (j > i))) * 4 + k];
        rtS[k][j] = v;
    }
    // Rf: unpack receiver R row to f32 — 4 elems/thread
    {
        const int k = tid >> 6, e4 = tid & 63;
        u16x4 t4 = *(const u16x4*)&R[((size_t)(k * 2048 + b * 64 + i)) * 256 + e4 * 4];
#pragma unroll
        for (int e = 0; e < 4; ++e) Rf[k][e4 * 4 + e] = bf2f(t4[e]);
    }
    __syncthreads();

    // B base for this lane's n-quarter (coalesced 16B/lane, L2-resident)
    const u16* Wb = W2t + lh * 2048 + (w * 64 + l31) * 8;

    float amsg[2] = {0.f, 0.f};

    for (int kT = 0; kT < 4; ++kT) {
        // ---- build H(kT): 64 rows x 256 kk, unique work, conflict-free writes ----
        // thread (row=lane, wq=w) fills slots g = s*4+w, s=0..7  (kk = g*8..g*8+7)
#pragma unroll
        for (int s = 0; s < 8; ++s) {
            u16x8 sv = *(const u16x8*)&S2[((size_t)((kT * 8 + s) * 2048 + b * 64 + lane)) * 32 + w * 8];
            const float* rp = &Rf[kT][s * 32 + w * 8];
            f32x4 r0 = *(const f32x4*)rp, r1 = *(const f32x4*)(rp + 4);
            bf16x8 o;
#pragma unroll
            for (int e = 0; e < 4; ++e) {
                o[e]     = (__bf16)fmaxf(r0[e] + bf2f(sv[e]),     0.f);
                o[4 + e] = (__bf16)fmaxf(r1[e] + bf2f(sv[4 + e]), 0.f);
            }
            *(bf16x8*)&Hs[s * 4 + w][lane][0] = o;
        }
        __syncthreads();   // H(kT) visible

        // ---- MFMA phase: 8 straight-line iters, no barriers ----
        f32x16 acc[2][2];
#pragma unroll
        for (int mt = 0; mt < 2; ++mt)
#pragma unroll
            for (int nt = 0; nt < 2; ++nt) acc[mt][nt] = (f32x16)(0.f);

#pragma unroll
        for (int kc = 0; kc < 8; ++kc) {
            const int it = kT * 8 + kc;
#pragma unroll
            for (int ks2 = 0; ks2 < 2; ++ks2) {
                const int g = kc * 4 + ks2 * 2 + lh;
                bf16x8 A0 = *(const bf16x8*)&Hs[g][l31][0];
                bf16x8 A1 = *(const bf16x8*)&Hs[g][32 + l31][0];
                const u16* wp = Wb + (size_t)it * 8192 + ks2 * 4096;
                bf16x8 B0 = *(const bf16x8*)(wp);
                bf16x8 B1 = *(const bf16x8*)(wp + 256);
                acc[0][0] = __builtin_amdgcn_mfma_f32_32x32x16_bf16(A0, B0, acc[0][0], 0, 0, 0);
                acc[0][1] = __builtin_amdgcn_mfma_f32_32x32x16_bf16(A0, B1, acc[0][1], 0, 0, 0);
                acc[1][0] = __builtin_amdgcn_mfma_f32_32x32x16_bf16(A1, B0, acc[1][0], 0, 0, 0);
                acc[1][1] = __builtin_amdgcn_mfma_f32_32x32x16_bf16(A1, B1, acc[1][1], 0, 0, 0);
            }
        }

        // ---- per-k epilogue: bias + relu + rel_type-weighted row fold ----
#pragma unroll
        for (int nt = 0; nt < 2; ++nt) {
            const float bias = b2[kT * 256 + w * 64 + nt * 32 + l31];
#pragma unroll
            for (int mt = 0; mt < 2; ++mt) {
                float s = 0.f;
#pragma unroll
                for (int rq = 0; rq < 4; ++rq) {
                    f32x4 rt4 = *(const f32x4*)&rtS[kT][mt * 32 + rq * 8 + 4 * lh];
#pragma unroll
                    for (int e = 0; e < 4; ++e) {
                        float v = acc[mt][nt][rq * 4 + e] + bias;
                        v = v > 0.f ? v : 0.f;
                        s += rt4[e] * v;
                    }
                }
                amsg[nt] += s;
            }
        }
        __syncthreads();   // all waves done reading Hs before next build
    }

    // fold lh halves; unique writer per slot
#pragma unroll
    for (int nt = 0; nt < 2; ++nt) {
        float s = amsg[nt] + __shfl_xor(amsg[nt], 32);
        if (lh == 0)
            aggb[(size_t)(b * 64 + i) * 256 + w * 64 + nt * 32 + l31] = f2bf(s);
    }
}

// ---------------- output MLP: reg-prefetched weight chunks + raw barriers ----------------
__global__ __launch_bounds__(256) void outmlp3_kernel(
    const float* __restrict__ x, const u16* __restrict__ aggb,
    const float* __restrict__ Wo1, const float* __restrict__ bo1,
    const float* __restrict__ Wo2, const float* __restrict__ bo2,
    const float* __restrict__ Wo3, const float* __restrict__ bo3,
    float* __restrict__ out)
{
    __shared__ u16 wch[4][256][8];   // cf weight chunk [g][n][8kk]
    __shared__ u16 p1S[32 * 264];
    __shared__ u16 p2S[32 * 264];
    const int tid = threadIdx.x, lane = tid & 63, w = tid >> 6;
    const int quad = lane >> 4, mloc = lane & 15;
    const int row0 = blockIdx.x * 32;

    {   // ---- L1: K=384 (12 chunks), N=256, aug=[x|agg] ----
        f32x4 acc[2][4];
#pragma unroll
        for (int mt = 0; mt < 2; ++mt)
#pragma unroll
            for (int nt = 0; nt < 4; ++nt) acc[mt][nt] = (f32x4){0.f, 0.f, 0.f, 0.f};
        float wr[32];
#pragma unroll
        for (int g = 0; g < 4; ++g)
#pragma unroll
            for (int e = 0; e < 8; ++e) wr[g * 8 + e] = Wo1[(g * 8 + e) * 256 + tid];
        for (int kk = 0; kk < 12; ++kk) {
            bf16x8 aF[2];
#pragma unroll
            for (int mt = 0; mt < 2; ++mt) {
                const int row = row0 + mt * 16 + mloc;
                if (kk < 4) {
                    u16x8 t;
#pragma unroll
                    for (int e = 0; e < 8; ++e) t[e] = f2bf(x[row * 128 + kk * 32 + quad * 8 + e]);
                    __builtin_memcpy(&aF[mt], &t, 16);
                } else {
                    aF[mt] = *(const bf16x8*)&aggb[(size_t)row * 256 + (kk - 4) * 32 + quad * 8];
                }
            }
#pragma unroll
            for (int g = 0; g < 4; ++g) {
                u16x8 o;
#pragma unroll
                for (int e = 0; e < 8; ++e) o[e] = f2bf(wr[g * 8 + e]);
                *(u16x8*)&wch[g][tid][0] = o;
            }
            if (kk + 1 < 12) {
#pragma unroll
                for (int g = 0; g < 4; ++g)
#pragma unroll
                    for (int e = 0; e < 8; ++e) wr[g * 8 + e] = Wo1[((kk + 1) * 32 + g * 8 + e) * 256 + tid];
            }
            LBAR();
#pragma unroll
            for (int nt = 0; nt < 4; ++nt) {
                bf16x8 bF = *(const bf16x8*)&wch[quad][w * 64 + nt * 16 + mloc][0];
#pragma unroll
                for (int mt = 0; mt < 2; ++mt)
                    acc[mt][nt] = __builtin_amdgcn_mfma_f32_16x16x32_bf16(aF[mt], bF, acc[mt][nt], 0, 0, 0);
            }
            LBAR();
        }
#pragma unroll
        for (int nt = 0; nt < 4; ++nt) {
            const int n = w * 64 + nt * 16 + mloc;
            const float bias = bo1[n];
#pragma unroll
            for (int mt = 0; mt < 2; ++mt)
#pragma unroll
                for (int r = 0; r < 4; ++r) {
                    float v = acc[mt][nt][r] + bias;
                    p1S[(mt * 16 + quad * 4 + r) * 264 + n] = f2bf(v > 0.f ? v : 0.f);
                }
        }
    }
    LBAR();
    {   // ---- L2: K=256 (8 chunks), N=256 ----
        f32x4 acc[2][4];
#pragma unroll
        for (int mt = 0; mt < 2; ++mt)
#pragma unroll
            for (int nt = 0; nt < 4; ++nt) acc[mt][nt] = (f32x4){0.f, 0.f, 0.f, 0.f};
        float wr[32];
#pragma unroll
        for (int g = 0; g < 4; ++g)
#pragma unroll
            for (int e = 0; e < 8; ++e) wr[g * 8 + e] = Wo2[(g * 8 + e) * 256 + tid];
        for (int kk = 0; kk < 8; ++kk) {
            bf16x8 aF[2];
#pragma unroll
            for (int mt = 0; mt < 2; ++mt)
                aF[mt] = *(const bf16x8*)&p1S[(mt * 16 + mloc) * 264 + kk * 32 + quad * 8];
#pragma unroll
            for (int g = 0; g < 4; ++g) {
                u16x8 o;
#pragma unroll
                for (int e = 0; e < 8; ++e) o[e] = f2bf(wr[g * 8 + e]);
                *(u16x8*)&wch[g][tid][0] = o;
            }
            if (kk + 1 < 8) {
#pragma unroll
                for (int g = 0; g < 4; ++g)
#pragma unroll
                    for (int e = 0; e < 8; ++e) wr[g * 8 + e] = Wo2[((kk + 1) * 32 + g * 8 + e) * 256 + tid];
            }
            LBAR();
#pragma unroll
            for (int nt = 0; nt < 4; ++nt) {
                bf16x8 bF = *(const bf16x8*)&wch[quad][w * 64 + nt * 16 + mloc][0];
#pragma unroll
                for (int mt = 0; mt < 2; ++mt)
                    acc[mt][nt] = __builtin_amdgcn_mfma_f32_16x16x32_bf16(aF[mt], bF, acc[mt][nt], 0, 0, 0);
            }
            LBAR();
        }
#pragma unroll
        for (int nt = 0; nt < 4; ++nt) {
            const int n = w * 64 + nt * 16 + mloc;
            const float bias = bo2[n];
#pragma unroll
            for (int mt = 0; mt < 2; ++mt)
#pragma unroll
                for (int r = 0; r < 4; ++r) {
                    float v = acc[mt][nt][r] + bias;
                    p2S[(mt * 16 + quad * 4 + r) * 264 + n] = f2bf(v > 0.f ? v : 0.f);
                }
        }
    }
    LBAR();
    {   // ---- L3: K=256 (8 chunks), N=128, residual ----
        f32x4 acc[2][2];
#pragma unroll
        for (int mt = 0; mt < 2; ++mt)
#pragma unroll
            for (int nt = 0; nt < 2; ++nt) acc[mt][nt] = (f32x4){0.f, 0.f, 0.f, 0.f};
        const int sn = tid & 127, sh = tid >> 7;
        float wr[16];
#pragma unroll
        for (int g2 = 0; g2 < 2; ++g2)
#pragma unroll
            for (int e = 0; e < 8; ++e) wr[g2 * 8 + e] = Wo3[((sh * 2 + g2) * 8 + e) * 128 + sn];
        for (int kk = 0; kk < 8; ++kk) {
            bf16x8 aF[2];
#pragma unroll
            for (int mt = 0; mt < 2; ++mt)
                aF[mt] = *(const bf16x8*)&p2S[(mt * 16 + mloc) * 264 + kk * 32 + quad * 8];
#pragma unroll
            for (int g2 = 0; g2 < 2; ++g2) {
                const int g = sh * 2 + g2;
                u16x8 o;
#pragma unroll
                for (int e = 0; e < 8; ++e) o[e] = f2bf(wr[g2 * 8 + e]);
                *(u16x8*)&wch[g][sn][0] = o;
            }
            if (kk + 1 < 8) {
#pragma unroll
                for (int g2 = 0; g2 < 2; ++g2)
#pragma unroll
                    for (int e = 0; e < 8; ++e)
                        wr[g2 * 8 + e] = Wo3[((kk + 1) * 32 + (sh * 2 + g2) * 8 + e) * 128 + sn];
            }
            LBAR();
#pragma unroll
            for (int nt = 0; nt < 2; ++nt) {
                bf16x8 bF = *(const bf16x8*)&wch[quad][w * 32 + nt * 16 + mloc][0];
#pragma unroll
                for (int mt = 0; mt < 2; ++mt)
                    acc[mt][nt] = __builtin_amdgcn_mfma_f32_16x16x32_bf16(aF[mt], bF, acc[mt][nt], 0, 0, 0);
            }
            LBAR();
        }
#pragma unroll
        for (int nt = 0; nt < 2; ++nt) {
            const int n = w * 32 + nt * 16 + mloc;
            const float bias = bo3[n];
#pragma unroll
            for (int mt = 0; mt < 2; ++mt)
#pragma unroll
                for (int r = 0; r < 4; ++r) {
                    const int grow = row0 + mt * 16 + quad * 4 + r;
                    out[grow * 128 + n] = x[grow * 128 + n] + acc[mt][nt][r] + bias;
                }
        }
    }
}

extern "C" void kernel_launch(void* const* d_in, const int* in_sizes, int n_in,
                              void* d_out, int out_size, void* d_ws, size_t ws_size,
                              hipStream_t stream) {
    const float* x   = (const float*)d_in[0];
    const float* rel = (const float*)d_in[1];
    const float* W1  = (const float*)d_in[4];
    const float* b1  = (const float*)d_in[5];
    const float* W2  = (const float*)d_in[6];
    const float* b2  = (const float*)d_in[7];
    const float* Wo1 = (const float*)d_in[8];
    const float* bo1 = (const float*)d_in[9];
    const float* Wo2 = (const float*)d_in[10];
    const float* bo2 = (const float*)d_in[11];
    const float* Wo3 = (const float*)d_in[12];
    const float* bo3 = (const float*)d_in[13];
    float* out = (float*)d_out;

    char* ws = (char*)d_ws;
    u16* W2t  = (u16*)(ws + WS_W2T);
    u16* R    = (u16*)(ws + WS_R);
    u16* S2   = (u16*)(ws + WS_S);
    u16* aggb = (u16*)(ws + WS_AGG);

    prep_rs_kernel<<<1280, 256, 0, stream>>>(W2, x, W1, b1, W2t, R, S2);
    edge11_kernel<<<2048, 256, 0, stream>>>(R, S2, rel, W2t, b2, aggb);
    outmlp3_kernel<<<64, 256, 0, stream>>>(x, aggb, Wo1, bo1, Wo2, bo2, Wo3, bo3, out);
}

// Round 7
// 196.142 us; speedup vs baseline: 1.1655x; 1.0556x over previous
//
#include <hip/hip_runtime.h>

// GraphDecoder (NRI) — round 16: edge12 = edge11 (per-kT staged H, 8 barriers,
// proven 94.7us) + explicit register pipelining: S2-next-kT reloaded into the
// SAME sreg regs during the MFMA phase (build becomes pure VALU), B fragments
// double-buffered one kc ahead in regs (static Bb[kc&1] indices), B(kT,0)
// issued before the build. No order-pinning. ~155 VGPR under (256,3).
// outmlp4: 512 threads (8 waves = 2/SIMD TLP; waves = row-half x n-quarter),
// halves per-wave serial work in the 28-chunk chain. prep unchanged.
// B=32, N=64, F=128, K=4, H=M=NH=256, E=4032.

#define B_ 32
#define N_ 64
#define F_ 128
#define K_ 4
#define E_ 4032

// ws layout (bytes): total 9,961,472 <= proven 9,994,240
#define WS_W2T 0u
#define WS_R   524288u
#define WS_S   4718592u
#define WS_AGG 8912896u

typedef unsigned short u16;
typedef u16    u16x4  __attribute__((ext_vector_type(4)));
typedef u16    u16x8  __attribute__((ext_vector_type(8)));
typedef __bf16 bf16x8 __attribute__((ext_vector_type(8)));
typedef float  f32x4  __attribute__((ext_vector_type(4)));
typedef float  f32x16 __attribute__((ext_vector_type(16)));

__device__ __forceinline__ u16 f2bf(float f) {
    unsigned u; __builtin_memcpy(&u, &f, 4);
    return (u16)((u + 0x7FFFu + ((u >> 16) & 1u)) >> 16);
}
__device__ __forceinline__ float bf2f(u16 u) {
    unsigned v = ((unsigned)u) << 16;
    float f; __builtin_memcpy(&f, &v, 4); return f;
}

// raw barrier (LDS-only handoff; keeps vmem prefetch in flight)
#define LBAR() do { \
    asm volatile("s_waitcnt lgkmcnt(0)" ::: "memory"); \
    __builtin_amdgcn_s_barrier(); \
    __builtin_amdgcn_sched_barrier(0); \
} while (0)

// ---------------- fused prep (W2 -> cf bf16 chunks) + R/S2 tables ----------------
// S2 kk-chunked: S2[((k*8+kc)*2048 + b*64 + row)*32 + kk_local]  (kc = kk>>5)
__global__ __launch_bounds__(256) void prep_rs_kernel(
    const float* __restrict__ W2, const float* __restrict__ x,
    const float* __restrict__ W1, const float* __restrict__ b1,
    u16* __restrict__ W2t, u16* __restrict__ R, u16* __restrict__ S)
{
    __shared__ u16 ldsA[64 * 136];
    __shared__ u16 ldsW[32 * 136];
    const int tid = threadIdx.x;

    if (blockIdx.x < 1024) {
        // W2t[chunk=k*8+kc][g=ks2*2+lh][n(256)][e(8)] = W2[k][kk][n]
        unsigned gid = blockIdx.x * 256u + tid;
        unsigned chunk = gid >> 13, r = gid & 8191u;
        unsigned g = r >> 11, n = (r >> 3) & 255u, e = r & 7u;
        unsigned k = chunk >> 3, kc = chunk & 7u, ks2 = g >> 1, lhh = g & 1u;
        unsigned kk = kc * 32u + ks2 * 16u + lhh * 8u + e;
        W2t[gid] = f2bf(W2[(k * 256u + kk) * 256u + n]);
        return;
    }

    const int lane = tid & 63, w = tid >> 6;
    const int quad = lane >> 4, mloc = lane & 15;
    const int bx = blockIdx.x - 1024;
    const int k = bx >> 6, half = (bx >> 5) & 1, b = bx & 31;

    for (int idx = tid; idx < 2048; idx += 256) {
        int row = idx >> 5, c4 = idx & 31;
        f32x4 v = *(const f32x4*)&x[(b * 64 + row) * 128 + c4 * 4];
        u16x4 o;
#pragma unroll
        for (int e = 0; e < 4; ++e) o[e] = f2bf(v[e]);
        *(u16x4*)&ldsA[row * 136 + c4 * 4] = o;
    }
    __syncthreads();

    bf16x8 aF[4];
#pragma unroll
    for (int ks = 0; ks < 4; ++ks)
        aF[ks] = *(const bf16x8*)&ldsA[(w * 16 + mloc) * 136 + quad * 8 + ks * 32];

    u16* dst = half ? S : R;
    for (int c = 0; c < 8; ++c) {
        __syncthreads();
        for (int idx = tid; idx < 4096; idx += 256) {
            int n = idx & 31, f = idx >> 5;
            ldsW[n * 136 + f] = f2bf(W1[(k * 256 + half * 128 + f) * 256 + c * 32 + n]);
        }
        __syncthreads();
#pragma unroll
        for (int nt = 0; nt < 2; ++nt) {
            f32x4 acc = (f32x4){0.f, 0.f, 0.f, 0.f};
            const int boff = (nt * 16 + mloc) * 136 + quad * 8;
#pragma unroll
            for (int ks = 0; ks < 4; ++ks)
                acc = __builtin_amdgcn_mfma_f32_16x16x32_bf16(
                    aF[ks], *(const bf16x8*)&ldsW[boff + ks * 32], acc, 0, 0, 0);
            const int n = c * 32 + nt * 16 + mloc;
            const float bias = half ? 0.f : b1[k * 256 + n];
#pragma unroll
            for (int r = 0; r < 4; ++r) {
                int row = w * 16 + quad * 4 + r;
                if (half) {
                    dst[((size_t)((k * 8 + c) * 2048 + b * 64 + row)) * 32 + nt * 16 + mloc]
                        = f2bf(acc[r] + bias);
                } else {
                    dst[((size_t)(k * 2048 + b * 64 + row)) * 256 + n] = f2bf(acc[r] + bias);
                }
            }
        }
    }
}

// ---------------- edge kernel: per-kT staged H + register pipelining ----------------
__global__ __launch_bounds__(256, 3) void edge12_kernel(
    const u16* __restrict__ R, const u16* __restrict__ S2,
    const float* __restrict__ rel, const u16* __restrict__ W2t,
    const float* __restrict__ b2, u16* __restrict__ aggb)
{
    __shared__ u16   Hs[32][64][8];   // H tile for one kT: [g=kk-group][row][8kk] — 32KB
    __shared__ float Rf[4][256];      // receiver R rows, f32 — written once
    __shared__ float rtS[4][64];      // rel_type [k][j], self=0 — written once

    const int tid  = threadIdx.x;
    const int lane = tid & 63;
    const int w    = tid >> 6;        // n-quarter (MFMA) AND kk32-subgroup (build)
    const int l31  = lane & 31;
    const int lh   = lane >> 5;
    // XCD-aware swizzle (bijective: 2048 % 8 == 0): 64 blocks sharing b per XCD
    // -> S2/R/rel/W2t slices L2-resident (FETCH 22.4->8MB proven R10/R11).
    const int bid  = ((blockIdx.x & 7) << 8) | (blockIdx.x >> 3);
    const int b    = bid >> 6;
    const int i    = bid & 63;        // receiver node

    // rtS: self-edge trick (j==i -> 0; else jj = j - (j>i)) — 1 elem/thread
    {
        const int k = tid >> 6, j = tid & 63;
        float v = 0.f;
        if (j != i) v = rel[((size_t)(b * E_) + i * 63 + (j - (j > i))) * 4 + k];
        rtS[k][j] = v;
    }
    // Rf: unpack receiver R row to f32 — 4 elems/thread
    {
        const int k = tid >> 6, e4 = tid & 63;
        u16x4 t4 = *(const u16x4*)&R[((size_t)(k * 2048 + b * 64 + i)) * 256 + e4 * 4];
#pragma unroll
        for (int e = 0; e < 4; ++e) Rf[k][e4 * 4 + e] = bf2f(t4[e]);
    }

    // S2 slices for kT=0 preloaded into regs (8 x 16B, reloaded in-place per kT)
    u16x8 sreg[8];
#pragma unroll
    for (int s = 0; s < 8; ++s)
        sreg[s] = *(const u16x8*)&S2[((size_t)(s * 2048 + b * 64 + lane)) * 32 + w * 8];

    __syncthreads();

    // B base for this lane's n-quarter (coalesced 16B/lane, L2-resident)
    const u16* Wb = W2t + lh * 2048 + (w * 64 + l31) * 8;

    float amsg[2] = {0.f, 0.f};

    for (int kT = 0; kT < 4; ++kT) {
        // preload B(kT, kc=0) — latency hides under the build VALU
        bf16x8 Bb[2][2][2];   // [kc parity][ks2][nt] — all indices static (unrolled)
#pragma unroll
        for (int ks2 = 0; ks2 < 2; ++ks2) {
            const u16* wp = Wb + (size_t)(kT * 8) * 8192 + ks2 * 4096;
            Bb[0][ks2][0] = *(const bf16x8*)(wp);
            Bb[0][ks2][1] = *(const bf16x8*)(wp + 256);
        }
        // ---- build H(kT) from sreg: pure VALU, conflict-free writes ----
#pragma unroll
        for (int s = 0; s < 8; ++s) {
            const float* rp = &Rf[kT][s * 32 + w * 8];
            f32x4 r0 = *(const f32x4*)rp, r1 = *(const f32x4*)(rp + 4);
            bf16x8 o;
#pragma unroll
            for (int e = 0; e < 4; ++e) {
                o[e]     = (__bf16)fmaxf(r0[e] + bf2f(sreg[s][e]),     0.f);
                o[4 + e] = (__bf16)fmaxf(r1[e] + bf2f(sreg[s][4 + e]), 0.f);
            }
            *(bf16x8*)&Hs[s * 4 + w][lane][0] = o;
        }
        __syncthreads();   // H(kT) visible

        // ---- MFMA phase: 8 straight-line iters, B one-kc-ahead in regs ----
        f32x16 acc[2][2];
#pragma unroll
        for (int mt = 0; mt < 2; ++mt)
#pragma unroll
            for (int nt = 0; nt < 2; ++nt) acc[mt][nt] = (f32x16)(0.f);

#pragma unroll
        for (int kc = 0; kc < 8; ++kc) {
            const int cur = kc & 1, nxt = cur ^ 1;
            // reload sreg for kT+1 (regs are dead after the build consumed them)
            if (kc == 0 && kT < 3) {
#pragma unroll
                for (int s = 0; s < 8; ++s)
                    sreg[s] = *(const u16x8*)&S2[((size_t)(((kT + 1) * 8 + s) * 2048 + b * 64 + lane)) * 32 + w * 8];
            }
            // prefetch B(kc+1)
            if (kc < 7) {
#pragma unroll
                for (int ks2 = 0; ks2 < 2; ++ks2) {
                    const u16* wp = Wb + (size_t)(kT * 8 + kc + 1) * 8192 + ks2 * 4096;
                    Bb[nxt][ks2][0] = *(const bf16x8*)(wp);
                    Bb[nxt][ks2][1] = *(const bf16x8*)(wp + 256);
                }
            }
#pragma unroll
            for (int ks2 = 0; ks2 < 2; ++ks2) {
                const int g = kc * 4 + ks2 * 2 + lh;
                bf16x8 A0 = *(const bf16x8*)&Hs[g][l31][0];
                bf16x8 A1 = *(const bf16x8*)&Hs[g][32 + l31][0];
                acc[0][0] = __builtin_amdgcn_mfma_f32_32x32x16_bf16(A0, Bb[cur][ks2][0], acc[0][0], 0, 0, 0);
                acc[0][1] = __builtin_amdgcn_mfma_f32_32x32x16_bf16(A0, Bb[cur][ks2][1], acc[0][1], 0, 0, 0);
                acc[1][0] = __builtin_amdgcn_mfma_f32_32x32x16_bf16(A1, Bb[cur][ks2][0], acc[1][0], 0, 0, 0);
                acc[1][1] = __builtin_amdgcn_mfma_f32_32x32x16_bf16(A1, Bb[cur][ks2][1], acc[1][1], 0, 0, 0);
            }
        }

        // ---- per-k epilogue: bias + relu + rel_type-weighted row fold ----
#pragma unroll
        for (int nt = 0; nt < 2; ++nt) {
            const float bias = b2[kT * 256 + w * 64 + nt * 32 + l31];
#pragma unroll
            for (int mt = 0; mt < 2; ++mt) {
                float s = 0.f;
#pragma unroll
                for (int rq = 0; rq < 4; ++rq) {
                    f32x4 rt4 = *(const f32x4*)&rtS[kT][mt * 32 + rq * 8 + 4 * lh];
#pragma unroll
                    for (int e = 0; e < 4; ++e) {
                        float v = acc[mt][nt][rq * 4 + e] + bias;
                        v = v > 0.f ? v : 0.f;
                        s += rt4[e] * v;
                    }
                }
                amsg[nt] += s;
            }
        }
        __syncthreads();   // all waves done reading Hs before next build
    }

    // fold lh halves; unique writer per slot
#pragma unroll
    for (int nt = 0; nt < 2; ++nt) {
        float s = amsg[nt] + __shfl_xor(amsg[nt], 32);
        if (lh == 0)
            aggb[(size_t)(b * 64 + i) * 256 + w * 64 + nt * 32 + l31] = f2bf(s);
    }
}

// ---------------- output MLP: 512 threads (2 waves/SIMD TLP), reg-prefetched ----------------
__global__ __launch_bounds__(512) void outmlp4_kernel(
    const float* __restrict__ x, const u16* __restrict__ aggb,
    const float* __restrict__ Wo1, const float* __restrict__ bo1,
    const float* __restrict__ Wo2, const float* __restrict__ bo2,
    const float* __restrict__ Wo3, const float* __restrict__ bo3,
    float* __restrict__ out)
{
    __shared__ u16 wch[4][256][8];   // cf weight chunk [g][n][8kk]
    __shared__ u16 p1S[32 * 264];
    __shared__ u16 p2S[32 * 264];
    const int tid  = threadIdx.x, lane = tid & 63;
    const int w8   = tid >> 6;       // wave 0..7
    const int mh   = w8 >> 2;        // row-half 0..1
    const int w4   = w8 & 3;         // n-quarter 0..3
    const int quad = lane >> 4, mloc = lane & 15;
    const int row0 = blockIdx.x * 32;
    const int sg2  = (tid >> 8) * 2; // staging base g (0 or 2)
    const int sn   = tid & 255;      // staging col

    {   // ---- L1: K=384 (12 chunks), N=256, aug=[x|agg] ----
        f32x4 acc[4];
#pragma unroll
        for (int nt = 0; nt < 4; ++nt) acc[nt] = (f32x4){0.f, 0.f, 0.f, 0.f};
        float wr[16];
#pragma unroll
        for (int g2 = 0; g2 < 2; ++g2)
#pragma unroll
            for (int e = 0; e < 8; ++e) wr[g2 * 8 + e] = Wo1[((sg2 + g2) * 8 + e) * 256 + sn];
        for (int kk = 0; kk < 12; ++kk) {
            bf16x8 aF;
            {
                const int row = row0 + mh * 16 + mloc;
                if (kk < 4) {
                    u16x8 t;
#pragma unroll
                    for (int e = 0; e < 8; ++e) t[e] = f2bf(x[row * 128 + kk * 32 + quad * 8 + e]);
                    __builtin_memcpy(&aF, &t, 16);
                } else {
                    aF = *(const bf16x8*)&aggb[(size_t)row * 256 + (kk - 4) * 32 + quad * 8];
                }
            }
#pragma unroll
            for (int g2 = 0; g2 < 2; ++g2) {
                u16x8 o;
#pragma unroll
                for (int e = 0; e < 8; ++e) o[e] = f2bf(wr[g2 * 8 + e]);
                *(u16x8*)&wch[sg2 + g2][sn][0] = o;
            }
            if (kk + 1 < 12) {
#pragma unroll
                for (int g2 = 0; g2 < 2; ++g2)
#pragma unroll
                    for (int e = 0; e < 8; ++e)
                        wr[g2 * 8 + e] = Wo1[((kk + 1) * 32 + (sg2 + g2) * 8 + e) * 256 + sn];
            }
            LBAR();
#pragma unroll
            for (int nt = 0; nt < 4; ++nt) {
                bf16x8 bF = *(const bf16x8*)&wch[quad][w4 * 64 + nt * 16 + mloc][0];
                acc[nt] = __builtin_amdgcn_mfma_f32_16x16x32_bf16(aF, bF, acc[nt], 0, 0, 0);
            }
            LBAR();
        }
#pragma unroll
        for (int nt = 0; nt < 4; ++nt) {
            const int n = w4 * 64 + nt * 16 + mloc;
            const float bias = bo1[n];
#pragma unroll
            for (int r = 0; r < 4; ++r) {
                float v = acc[nt][r] + bias;
                p1S[(mh * 16 + quad * 4 + r) * 264 + n] = f2bf(v > 0.f ? v : 0.f);
            }
        }
    }
    LBAR();
    {   // ---- L2: K=256 (8 chunks), N=256 ----
        f32x4 acc[4];
#pragma unroll
        for (int nt = 0; nt < 4; ++nt) acc[nt] = (f32x4){0.f, 0.f, 0.f, 0.f};
        float wr[16];
#pragma unroll
        for (int g2 = 0; g2 < 2; ++g2)
#pragma unroll
            for (int e = 0; e < 8; ++e) wr[g2 * 8 + e] = Wo2[((sg2 + g2) * 8 + e) * 256 + sn];
        for (int kk = 0; kk < 8; ++kk) {
            bf16x8 aF = *(const bf16x8*)&p1S[(mh * 16 + mloc) * 264 + kk * 32 + quad * 8];
#pragma unroll
            for (int g2 = 0; g2 < 2; ++g2) {
                u16x8 o;
#pragma unroll
                for (int e = 0; e < 8; ++e) o[e] = f2bf(wr[g2 * 8 + e]);
                *(u16x8*)&wch[sg2 + g2][sn][0] = o;
            }
            if (kk + 1 < 8) {
#pragma unroll
                for (int g2 = 0; g2 < 2; ++g2)
#pragma unroll
                    for (int e = 0; e < 8; ++e)
                        wr[g2 * 8 + e] = Wo2[((kk + 1) * 32 + (sg2 + g2) * 8 + e) * 256 + sn];
            }
            LBAR();
#pragma unroll
            for (int nt = 0; nt < 4; ++nt) {
                bf16x8 bF = *(const bf16x8*)&wch[quad][w4 * 64 + nt * 16 + mloc][0];
                acc[nt] = __builtin_amdgcn_mfma_f32_16x16x32_bf16(aF, bF, acc[nt], 0, 0, 0);
            }
            LBAR();
        }
#pragma unroll
        for (int nt = 0; nt < 4; ++nt) {
            const int n = w4 * 64 + nt * 16 + mloc;
            const float bias = bo2[n];
#pragma unroll
            for (int r = 0; r < 4; ++r) {
                float v = acc[nt][r] + bias;
                p2S[(mh * 16 + quad * 4 + r) * 264 + n] = f2bf(v > 0.f ? v : 0.f);
            }
        }
    }
    LBAR();
    {   // ---- L3: K=256 (8 chunks), N=128, residual ----
        f32x4 acc[2];
#pragma unroll
        for (int nt = 0; nt < 2; ++nt) acc[nt] = (f32x4){0.f, 0.f, 0.f, 0.f};
        const int sg3 = tid >> 7;    // 0..3, one g per thread-half-wave group
        const int sn3 = tid & 127;
        float wr[8];
#pragma unroll
        for (int e = 0; e < 8; ++e) wr[e] = Wo3[(sg3 * 8 + e) * 128 + sn3];
        for (int kk = 0; kk < 8; ++kk) {
            bf16x8 aF = *(const bf16x8*)&p2S[(mh * 16 + mloc) * 264 + kk * 32 + quad * 8];
            {
                u16x8 o;
#pragma unroll
                for (int e = 0; e < 8; ++e) o[e] = f2bf(wr[e]);
                *(u16x8*)&wch[sg3][sn3][0] = o;
            }
            if (kk + 1 < 8) {
#pragma unroll
                for (int e = 0; e < 8; ++e)
                    wr[e] = Wo3[((kk + 1) * 32 + sg3 * 8 + e) * 128 + sn3];
            }
            LBAR();
#pragma unroll
            for (int nt = 0; nt < 2; ++nt) {
                bf16x8 bF = *(const bf16x8*)&wch[quad][w4 * 32 + nt * 16 + mloc][0];
                acc[nt] = __builtin_amdgcn_mfma_f32_16x16x32_bf16(aF, bF, acc[nt], 0, 0, 0);
            }
            LBAR();
        }
#pragma unroll
        for (int nt = 0; nt < 2; ++nt) {
            const int n = w4 * 32 + nt * 16 + mloc;
            const float bias = bo3[n];
#pragma unroll
            for (int r = 0; r < 4; ++r) {
                const int grow = row0 + mh * 16 + quad * 4 + r;
                out[grow * 128 + n] = x[grow * 128 + n] + acc[nt][r] + bias;
            }
        }
    }
}

extern "C" void kernel_launch(void* const* d_in, const int* in_sizes, int n_in,
                              void* d_out, int out_size, void* d_ws, size_t ws_size,
                              hipStream_t stream) {
    const float* x   = (const float*)d_in[0];
    const float* rel = (const float*)d_in[1];
    const float* W1  = (const float*)d_in[4];
    const float* b1  = (const float*)d_in[5];
    const float* W2  = (const float*)d_in[6];
    const float* b2  = (const float*)d_in[7];
    const float* Wo1 = (const float*)d_in[8];
    const float* bo1 = (const float*)d_in[9];
    const float* Wo2 = (const float*)d_in[10];
    const float* bo2 = (const float*)d_in[11];
    const float* Wo3 = (const float*)d_in[12];
    const float* bo3 = (const float*)d_in[13];
    float* out = (float*)d_out;

    char* ws = (char*)d_ws;
    u16* W2t  = (u16*)(ws + WS_W2T);
    u16* R    = (u16*)(ws + WS_R);
    u16* S2   = (u16*)(ws + WS_S);
    u16* aggb = (u16*)(ws + WS_AGG);

    prep_rs_kernel<<<1280, 256, 0, stream>>>(W2, x, W1, b1, W2t, R, S2);
    edge12_kernel<<<2048, 256, 0, stream>>>(R, S2, rel, W2t, b2, aggb);
    outmlp4_kernel<<<64, 512, 0, stream>>>(x, aggb, Wo1, bo1, Wo2, bo2, Wo3, bo3, out);
}

// Round 8
// 193.314 us; speedup vs baseline: 1.1826x; 1.0146x over previous
//
#include <hip/hip_runtime.h>

// GraphDecoder (NRI) — round 17: attack the non-edge half (≈106us > edge 90us).
// prep: part-1 W2t conversion remapped linear-READ/scattered-write (was 16x
// read amplification: e-fastest gave 1KB-stride reads); part-2 R/S split
// across 2x blocks (512 blocks, 4 c-chunks each) for TLP.
// outmlp5: barrier-free layers — B-fragments built per-lane directly from
// global f32 weights (L2-resident, lane-coalesced), NO weight LDS staging,
// 2 barriers total (p1/p2 handoffs); 128 blocks x 16 rows (2x CU coverage).
// edge12 unchanged (90.2us proven). B=32,N=64,F=128,K=4,H=M=NH=256,E=4032.

#define B_ 32
#define N_ 64
#define F_ 128
#define K_ 4
#define E_ 4032

// ws layout (bytes): total 9,961,472 <= proven 9,994,240
#define WS_W2T 0u
#define WS_R   524288u
#define WS_S   4718592u
#define WS_AGG 8912896u

typedef unsigned short u16;
typedef u16    u16x4  __attribute__((ext_vector_type(4)));
typedef u16    u16x8  __attribute__((ext_vector_type(8)));
typedef __bf16 bf16x8 __attribute__((ext_vector_type(8)));
typedef float  f32x4  __attribute__((ext_vector_type(4)));
typedef float  f32x16 __attribute__((ext_vector_type(16)));

__device__ __forceinline__ u16 f2bf(float f) {
    unsigned u; __builtin_memcpy(&u, &f, 4);
    return (u16)((u + 0x7FFFu + ((u >> 16) & 1u)) >> 16);
}
__device__ __forceinline__ float bf2f(u16 u) {
    unsigned v = ((unsigned)u) << 16;
    float f; __builtin_memcpy(&f, &v, 4); return f;
}

// raw barrier (LDS-only handoff; keeps vmem prefetch in flight)
#define LBAR() do { \
    asm volatile("s_waitcnt lgkmcnt(0)" ::: "memory"); \
    __builtin_amdgcn_s_barrier(); \
    __builtin_amdgcn_sched_barrier(0); \
} while (0)

// ---------------- fused prep (W2 -> cf bf16 chunks) + R/S2 tables ----------------
// S2 kk-chunked: S2[((k*8+kc)*2048 + b*64 + row)*32 + kk_local]  (kc = kk>>5)
__global__ __launch_bounds__(256) void prep_rs_kernel(
    const float* __restrict__ W2, const float* __restrict__ x,
    const float* __restrict__ W1, const float* __restrict__ b1,
    u16* __restrict__ W2t, u16* __restrict__ R, u16* __restrict__ S)
{
    __shared__ u16 ldsA[64 * 136];
    __shared__ u16 ldsW[32 * 136];
    const int tid = threadIdx.x;

    if (blockIdx.x < 1024) {
        // linear read of W2 (coalesced); scattered 2B writes (fire-and-forget).
        // gid = (k*256+kk)*256+n ; kk bits: [7:5]=kc [4]=ks2 [3]=lhh [2:0]=e
        // dst = (k*8+kc)*8192 + (ks2*2+lhh)*2048 + n*8 + e
        unsigned gid = blockIdx.x * 256u + tid;
        unsigned n = gid & 255u, kk = (gid >> 8) & 255u, k = gid >> 16;
        unsigned dst = (k * 8u + (kk >> 5)) * 8192u
                     + ((((kk >> 4) & 1u) * 2u) + ((kk >> 3) & 1u)) * 2048u
                     + n * 8u + (kk & 7u);
        W2t[dst] = f2bf(W2[gid]);
        return;
    }

    // part 2: R/S tables. 512 blocks: (k, half, b) x ch; ch covers 4 c-chunks.
    const int lane = tid & 63, w = tid >> 6;
    const int quad = lane >> 4, mloc = lane & 15;
    const int bx = blockIdx.x - 1024;
    const int ch = bx & 1;
    const int bq = bx >> 1;
    const int k = bq >> 6, half = (bq >> 5) & 1, b = bq & 31;

    for (int idx = tid; idx < 2048; idx += 256) {
        int row = idx >> 5, c4 = idx & 31;
        f32x4 v = *(const f32x4*)&x[(b * 64 + row) * 128 + c4 * 4];
        u16x4 o;
#pragma unroll
        for (int e = 0; e < 4; ++e) o[e] = f2bf(v[e]);
        *(u16x4*)&ldsA[row * 136 + c4 * 4] = o;
    }
    __syncthreads();

    bf16x8 aF[4];
#pragma unroll
    for (int ks = 0; ks < 4; ++ks)
        aF[ks] = *(const bf16x8*)&ldsA[(w * 16 + mloc) * 136 + quad * 8 + ks * 32];

    u16* dst = half ? S : R;
    for (int c = ch * 4; c < ch * 4 + 4; ++c) {
        __syncthreads();
        for (int idx = tid; idx < 4096; idx += 256) {
            int n = idx & 31, f = idx >> 5;
            ldsW[n * 136 + f] = f2bf(W1[(k * 256 + half * 128 + f) * 256 + c * 32 + n]);
        }
        __syncthreads();
#pragma unroll
        for (int nt = 0; nt < 2; ++nt) {
            f32x4 acc = (f32x4){0.f, 0.f, 0.f, 0.f};
            const int boff = (nt * 16 + mloc) * 136 + quad * 8;
#pragma unroll
            for (int ks = 0; ks < 4; ++ks)
                acc = __builtin_amdgcn_mfma_f32_16x16x32_bf16(
                    aF[ks], *(const bf16x8*)&ldsW[boff + ks * 32], acc, 0, 0, 0);
            const int n = c * 32 + nt * 16 + mloc;
            const float bias = half ? 0.f : b1[k * 256 + n];
#pragma unroll
            for (int r = 0; r < 4; ++r) {
                int row = w * 16 + quad * 4 + r;
                if (half) {
                    dst[((size_t)((k * 8 + c) * 2048 + b * 64 + row)) * 32 + nt * 16 + mloc]
                        = f2bf(acc[r] + bias);
                } else {
                    dst[((size_t)(k * 2048 + b * 64 + row)) * 256 + n] = f2bf(acc[r] + bias);
                }
            }
        }
    }
}

// ---------------- edge kernel: per-kT staged H + register pipelining (R16-proven) ----------------
__global__ __launch_bounds__(256, 3) void edge12_kernel(
    const u16* __restrict__ R, const u16* __restrict__ S2,
    const float* __restrict__ rel, const u16* __restrict__ W2t,
    const float* __restrict__ b2, u16* __restrict__ aggb)
{
    __shared__ u16   Hs[32][64][8];   // H tile for one kT: [g=kk-group][row][8kk] — 32KB
    __shared__ float Rf[4][256];      // receiver R rows, f32 — written once
    __shared__ float rtS[4][64];      // rel_type [k][j], self=0 — written once

    const int tid  = threadIdx.x;
    const int lane = tid & 63;
    const int w    = tid >> 6;        // n-quarter (MFMA) AND kk32-subgroup (build)
    const int l31  = lane & 31;
    const int lh   = lane >> 5;
    const int bid  = ((blockIdx.x & 7) << 8) | (blockIdx.x >> 3);
    const int b    = bid >> 6;
    const int i    = bid & 63;        // receiver node

    {
        const int k = tid >> 6, j = tid & 63;
        float v = 0.f;
        if (j != i) v = rel[((size_t)(b * E_) + i * 63 + (j - (j > i))) * 4 + k];
        rtS[k][j] = v;
    }
    {
        const int k = tid >> 6, e4 = tid & 63;
        u16x4 t4 = *(const u16x4*)&R[((size_t)(k * 2048 + b * 64 + i)) * 256 + e4 * 4];
#pragma unroll
        for (int e = 0; e < 4; ++e) Rf[k][e4 * 4 + e] = bf2f(t4[e]);
    }

    u16x8 sreg[8];
#pragma unroll
    for (int s = 0; s < 8; ++s)
        sreg[s] = *(const u16x8*)&S2[((size_t)(s * 2048 + b * 64 + lane)) * 32 + w * 8];

    __syncthreads();

    const u16* Wb = W2t + lh * 2048 + (w * 64 + l31) * 8;

    float amsg[2] = {0.f, 0.f};

    for (int kT = 0; kT < 4; ++kT) {
        bf16x8 Bb[2][2][2];
#pragma unroll
        for (int ks2 = 0; ks2 < 2; ++ks2) {
            const u16* wp = Wb + (size_t)(kT * 8) * 8192 + ks2 * 4096;
            Bb[0][ks2][0] = *(const bf16x8*)(wp);
            Bb[0][ks2][1] = *(const bf16x8*)(wp + 256);
        }
#pragma unroll
        for (int s = 0; s < 8; ++s) {
            const float* rp = &Rf[kT][s * 32 + w * 8];
            f32x4 r0 = *(const f32x4*)rp, r1 = *(const f32x4*)(rp + 4);
            bf16x8 o;
#pragma unroll
            for (int e = 0; e < 4; ++e) {
                o[e]     = (__bf16)fmaxf(r0[e] + bf2f(sreg[s][e]),     0.f);
                o[4 + e] = (__bf16)fmaxf(r1[e] + bf2f(sreg[s][4 + e]), 0.f);
            }
            *(bf16x8*)&Hs[s * 4 + w][lane][0] = o;
        }
        __syncthreads();

        f32x16 acc[2][2];
#pragma unroll
        for (int mt = 0; mt < 2; ++mt)
#pragma unroll
            for (int nt = 0; nt < 2; ++nt) acc[mt][nt] = (f32x16)(0.f);

#pragma unroll
        for (int kc = 0; kc < 8; ++kc) {
            const int cur = kc & 1, nxt = cur ^ 1;
            if (kc == 0 && kT < 3) {
#pragma unroll
                for (int s = 0; s < 8; ++s)
                    sreg[s] = *(const u16x8*)&S2[((size_t)(((kT + 1) * 8 + s) * 2048 + b * 64 + lane)) * 32 + w * 8];
            }
            if (kc < 7) {
#pragma unroll
                for (int ks2 = 0; ks2 < 2; ++ks2) {
                    const u16* wp = Wb + (size_t)(kT * 8 + kc + 1) * 8192 + ks2 * 4096;
                    Bb[nxt][ks2][0] = *(const bf16x8*)(wp);
                    Bb[nxt][ks2][1] = *(const bf16x8*)(wp + 256);
                }
            }
#pragma unroll
            for (int ks2 = 0; ks2 < 2; ++ks2) {
                const int g = kc * 4 + ks2 * 2 + lh;
                bf16x8 A0 = *(const bf16x8*)&Hs[g][l31][0];
                bf16x8 A1 = *(const bf16x8*)&Hs[g][32 + l31][0];
                acc[0][0] = __builtin_amdgcn_mfma_f32_32x32x16_bf16(A0, Bb[cur][ks2][0], acc[0][0], 0, 0, 0);
                acc[0][1] = __builtin_amdgcn_mfma_f32_32x32x16_bf16(A0, Bb[cur][ks2][1], acc[0][1], 0, 0, 0);
                acc[1][0] = __builtin_amdgcn_mfma_f32_32x32x16_bf16(A1, Bb[cur][ks2][0], acc[1][0], 0, 0, 0);
                acc[1][1] = __builtin_amdgcn_mfma_f32_32x32x16_bf16(A1, Bb[cur][ks2][1], acc[1][1], 0, 0, 0);
            }
        }

#pragma unroll
        for (int nt = 0; nt < 2; ++nt) {
            const float bias = b2[kT * 256 + w * 64 + nt * 32 + l31];
#pragma unroll
            for (int mt = 0; mt < 2; ++mt) {
                float s = 0.f;
#pragma unroll
                for (int rq = 0; rq < 4; ++rq) {
                    f32x4 rt4 = *(const f32x4*)&rtS[kT][mt * 32 + rq * 8 + 4 * lh];
#pragma unroll
                    for (int e = 0; e < 4; ++e) {
                        float v = acc[mt][nt][rq * 4 + e] + bias;
                        v = v > 0.f ? v : 0.f;
                        s += rt4[e] * v;
                    }
                }
                amsg[nt] += s;
            }
        }
        __syncthreads();
    }

#pragma unroll
    for (int nt = 0; nt < 2; ++nt) {
        float s = amsg[nt] + __shfl_xor(amsg[nt], 32);
        if (lh == 0)
            aggb[(size_t)(b * 64 + i) * 256 + w * 64 + nt * 32 + l31] = f2bf(s);
    }
}

// ---------------- output MLP: barrier-free layers, B from global f32 ----------------
// 128 blocks x 16 rows, 256 threads (4 waves = n-quarters). No weight LDS
// staging: each lane builds its B fragment from Wo* f32 (L2-resident; for a
// fixed e, 16 lanes read 64B contiguous). 2 barriers total (p1/p2 handoff).
__global__ __launch_bounds__(256) void outmlp5_kernel(
    const float* __restrict__ x, const u16* __restrict__ aggb,
    const float* __restrict__ Wo1, const float* __restrict__ bo1,
    const float* __restrict__ Wo2, const float* __restrict__ bo2,
    const float* __restrict__ Wo3, const float* __restrict__ bo3,
    float* __restrict__ out)
{
    __shared__ u16 p1S[16 * 264];
    __shared__ u16 p2S[16 * 264];
    const int tid = threadIdx.x, lane = tid & 63, w = tid >> 6;   // w = n-quarter
    const int quad = lane >> 4, mloc = lane & 15;
    const int row0 = blockIdx.x * 16;

    {   // ---- L1: K=384 (12 chunks), N=256, aug=[x|agg] ----
        f32x4 acc[4];
#pragma unroll
        for (int nt = 0; nt < 4; ++nt) acc[nt] = (f32x4){0.f, 0.f, 0.f, 0.f};
        for (int kk = 0; kk < 12; ++kk) {
            bf16x8 aF;
            const int row = row0 + mloc;
            if (kk < 4) {
                u16x8 t;
#pragma unroll
                for (int e = 0; e < 8; ++e) t[e] = f2bf(x[row * 128 + kk * 32 + quad * 8 + e]);
                __builtin_memcpy(&aF, &t, 16);
            } else {
                aF = *(const bf16x8*)&aggb[(size_t)row * 256 + (kk - 4) * 32 + quad * 8];
            }
#pragma unroll
            for (int nt = 0; nt < 4; ++nt) {
                const int n = w * 64 + nt * 16 + mloc;
                u16x8 t;
#pragma unroll
                for (int e = 0; e < 8; ++e)
                    t[e] = f2bf(Wo1[(kk * 32 + quad * 8 + e) * 256 + n]);
                bf16x8 bF;
                __builtin_memcpy(&bF, &t, 16);
                acc[nt] = __builtin_amdgcn_mfma_f32_16x16x32_bf16(aF, bF, acc[nt], 0, 0, 0);
            }
        }
#pragma unroll
        for (int nt = 0; nt < 4; ++nt) {
            const int n = w * 64 + nt * 16 + mloc;
            const float bias = bo1[n];
#pragma unroll
            for (int r = 0; r < 4; ++r) {
                float v = acc[nt][r] + bias;
                p1S[(quad * 4 + r) * 264 + n] = f2bf(v > 0.f ? v : 0.f);
            }
        }
    }
    LBAR();
    {   // ---- L2: K=256 (8 chunks), N=256 ----
        f32x4 acc[4];
#pragma unroll
        for (int nt = 0; nt < 4; ++nt) acc[nt] = (f32x4){0.f, 0.f, 0.f, 0.f};
        for (int kk = 0; kk < 8; ++kk) {
            bf16x8 aF = *(const bf16x8*)&p1S[mloc * 264 + kk * 32 + quad * 8];
#pragma unroll
            for (int nt = 0; nt < 4; ++nt) {
                const int n = w * 64 + nt * 16 + mloc;
                u16x8 t;
#pragma unroll
                for (int e = 0; e < 8; ++e)
                    t[e] = f2bf(Wo2[(kk * 32 + quad * 8 + e) * 256 + n]);
                bf16x8 bF;
                __builtin_memcpy(&bF, &t, 16);
                acc[nt] = __builtin_amdgcn_mfma_f32_16x16x32_bf16(aF, bF, acc[nt], 0, 0, 0);
            }
        }
#pragma unroll
        for (int nt = 0; nt < 4; ++nt) {
            const int n = w * 64 + nt * 16 + mloc;
            const float bias = bo2[n];
#pragma unroll
            for (int r = 0; r < 4; ++r) {
                float v = acc[nt][r] + bias;
                p2S[(quad * 4 + r) * 264 + n] = f2bf(v > 0.f ? v : 0.f);
            }
        }
    }
    LBAR();
    {   // ---- L3: K=256 (8 chunks), N=128, residual ----
        f32x4 acc[2];
#pragma unroll
        for (int nt = 0; nt < 2; ++nt) acc[nt] = (f32x4){0.f, 0.f, 0.f, 0.f};
        for (int kk = 0; kk < 8; ++kk) {
            bf16x8 aF = *(const bf16x8*)&p2S[mloc * 264 + kk * 32 + quad * 8];
#pragma unroll
            for (int nt = 0; nt < 2; ++nt) {
                const int n = w * 32 + nt * 16 + mloc;
                u16x8 t;
#pragma unroll
                for (int e = 0; e < 8; ++e)
                    t[e] = f2bf(Wo3[(kk * 32 + quad * 8 + e) * 128 + n]);
                bf16x8 bF;
                __builtin_memcpy(&bF, &t, 16);
                acc[nt] = __builtin_amdgcn_mfma_f32_16x16x32_bf16(aF, bF, acc[nt], 0, 0, 0);
            }
        }
#pragma unroll
        for (int nt = 0; nt < 2; ++nt) {
            const int n = w * 32 + nt * 16 + mloc;
            const float bias = bo3[n];
#pragma unroll
            for (int r = 0; r < 4; ++r) {
                const int grow = row0 + quad * 4 + r;
                out[grow * 128 + n] = x[grow * 128 + n] + acc[nt][r] + bias;
            }
        }
    }
}

extern "C" void kernel_launch(void* const* d_in, const int* in_sizes, int n_in,
                              void* d_out, int out_size, void* d_ws, size_t ws_size,
                              hipStream_t stream) {
    const float* x   = (const float*)d_in[0];
    const float* rel = (const float*)d_in[1];
    const float* W1  = (const float*)d_in[4];
    const float* b1  = (const float*)d_in[5];
    const float* W2  = (const float*)d_in[6];
    const float* b2  = (const float*)d_in[7];
    const float* Wo1 = (const float*)d_in[8];
    const float* bo1 = (const float*)d_in[9];
    const float* Wo2 = (const float*)d_in[10];
    const float* bo2 = (const float*)d_in[11];
    const float* Wo3 = (const float*)d_in[12];
    const float* bo3 = (const float*)d_in[13];
    float* out = (float*)d_out;

    char* ws = (char*)d_ws;
    u16* W2t  = (u16*)(ws + WS_W2T);
    u16* R    = (u16*)(ws + WS_R);
    u16* S2   = (u16*)(ws + WS_S);
    u16* aggb = (u16*)(ws + WS_AGG);

    prep_rs_kernel<<<1536, 256, 0, stream>>>(W2, x, W1, b1, W2t, R, S2);
    edge12_kernel<<<2048, 256, 0, stream>>>(R, S2, rel, W2t, b2, aggb);
    outmlp5_kernel<<<128, 256, 0, stream>>>(x, aggb, Wo1, bo1, Wo2, bo2, Wo3, bo3, out);
}